// Round 16
// baseline (1617.584 us; speedup 1.0000x reference)
//
#include <hip/hip_runtime.h>

// 2-layer LSTM (H=64, D=1), N=2048, T=512 — R16: DUAL-GROUP 4 waves/SIMD.
// 64 blocks x 1024 threads. Waves 0-7 = R15's E/O pipeline for samples
// [b*32, b*32+16); waves 8-15 = same for [b*32+16, b*32+32). Groups are
// data-independent, share one __syncthreads (equal barrier counts) -> each
// SIMD hosts E0,O0,E1,O1 = 4 independent latency chains that fill each
// other's stalls. Numeric core = R15 i8 2-level fixed-point MFMA, plus:
//  - exact int combine: gate_int = (S00 << 8) + SB (scales 2^-15/2^-23,
//    ratio exactly 2^8; |sum| < 2^28 -> exact i32) => 1 cvt + 1 fma/gate
//  - v_exp_f32 -src modifier folds the gate negations in cell2

typedef __attribute__((ext_vector_type(4))) int i32x4;
typedef __attribute__((ext_vector_type(4))) float f32x4;

#define XPITCH 2060              // 515 words (odd) -> conflict-free x reads
#define XPG 32960                // per-group x region (16 * 2060)
#define HB0 65920                // h planes: group q at HB0 + q*10240
#define HBG 10240
#define RING0 86400              // out ring: group q at RING0 + q*32768
#define LDS_BYTES 151936
#define L2E 1.44269504f
#define N2L2E (-2.8853900817779268f)

__device__ __forceinline__ float fast_rcp(float x) { return __builtin_amdgcn_rcpf(x); }
__device__ __forceinline__ float exp2_f(float x) {
  float r; asm("v_exp_f32 %0, %1" : "=v"(r) : "v"(x)); return r;
}
__device__ __forceinline__ float exp2_nf(float x) {  // 2^(-x), negate folded
  float r; asm("v_exp_f32 %0, -%1" : "=v"(r) : "v"(x)); return r;
}
__device__ __forceinline__ i32x4 mfma_i8(i32x4 a, i32x4 b, i32x4 c) {
  return __builtin_amdgcn_mfma_i32_16x16x64_i8(a, b, c, 0, 0, 0);
}
// gates pre-scaled: i,f,o by log2e; g by 2log2e. 5 exp2 + 3 rcp.
__device__ __forceinline__ void cell2(float i, float f, float g, float o,
                                      float& c, float& h) {
  const float ei = exp2_nf(i), ef = exp2_nf(f), eg = exp2_nf(g), eo = exp2_nf(o);
  const float P = (1.f - eg) * fast_rcp((1.f + ei) * (1.f + eg));
  c = fmaf(c, fast_rcp(1.f + ef), P);
  const float cc = fminf(15.f, fmaxf(-15.f, c));
  const float ec = exp2_f(N2L2E * cc);
  h = (1.f - ec) * fast_rcp((1.f + eo) * (1.f + ec));
}
// Quantize 16 consecutive f32 weights (|W|<=1/8) to two i8 levels, packed.
__device__ __forceinline__ void quantW16(const float* p, i32x4& w0v, i32x4& w1v) {
  int b0[16], b1[16];
#pragma unroll
  for (int e = 0; e < 16; ++e) {
    const float v = p[e];
    const float q0 = rintf(v * 512.f);
    const float r = v - q0 * (1.f / 512.f);
    const float q1 = fminf(127.f, fmaxf(-127.f, rintf(r * 131072.f)));
    b0[e] = (int)q0;
    b1[e] = (int)q1;
  }
#pragma unroll
  for (int d = 0; d < 4; ++d) {
    w0v[d] = (b0[4 * d] & 255) | ((b0[4 * d + 1] & 255) << 8) |
             ((b0[4 * d + 2] & 255) << 16) | ((b0[4 * d + 3] & 255) << 24);
    w1v[d] = (b1[4 * d] & 255) | ((b1[4 * d + 1] & 255) << 8) |
             ((b1[4 * d + 2] & 255) << 16) | ((b1[4 * d + 3] & 255) << 24);
  }
}
// Quantize 4 h values (|h|<=1) to two packed i8-level dwords.
__device__ __forceinline__ void quantH4(const float* h, unsigned& L0, unsigned& L1) {
  int q0[4], q1[4];
#pragma unroll
  for (int r = 0; r < 4; ++r) {
    const float q0f = rintf(h[r] * 64.f);
    q0[r] = (int)q0f;
    const float rr = h[r] - q0f * 0.015625f;
    const float q1f = fminf(127.f, fmaxf(-127.f, rintf(rr * 16384.f)));
    q1[r] = (int)q1f;
  }
  L0 = (q0[0] & 255) | ((q0[1] & 255) << 8) | ((q0[2] & 255) << 16) |
       ((q0[3] & 255) << 24);
  L1 = (q1[0] & 255) | ((q1[1] & 255) << 8) | ((q1[2] & 255) << 16) |
       ((q1[3] & 255) << 24);
}

__global__ __launch_bounds__(1024, 4) void lstm2_r16(
    const float* __restrict__ y, const float* __restrict__ Wih1,
    const float* __restrict__ Whh1, const float* __restrict__ bih1,
    const float* __restrict__ bhh1, const float* __restrict__ Wih2,
    const float* __restrict__ Whh2, const float* __restrict__ bih2,
    const float* __restrict__ bhh2, const float* __restrict__ Wlin,
    const float* __restrict__ blin, float* __restrict__ out) {
  extern __shared__ char smem[];
  const int tid = threadIdx.x;
  const int w = tid >> 6;          // wave 0..15
  const int q = w >> 3;            // sample group 0/1
  const int wr = w & 7;            // role wave within group (0-3 E, 4-7 O)
  const int lane = tid & 63;
  const int g = lane >> 4;
  const int s = lane & 15;
  const int s0g = blockIdx.x * 32 + q * 16;

  // ---- stage x for 32 samples ----
  for (int i = tid; i < 32 * 512; i += 1024) {
    const int ss = i >> 9, t = i & 511;
    *(float*)(smem + (ss >> 4) * XPG + (ss & 15) * XPITCH + t * 4) =
        y[(size_t)(blockIdx.x * 32 + ss) * 512 + t];
  }
  // ---- zero all h planes (both groups) ----
  for (int i = tid; i < 20480 / 4; i += 1024) *(float*)(smem + HB0 + i * 4) = 0.f;
  const float bl0 = blin[0];
  __syncthreads();

  const int hq = HB0 + q * HBG;                  // group plane base
  const int ringB = RING0 + q * 32768;           // group ring base
  const int boff = s * 80 + 16 * g;              // B-fragment byte offset
  const float gsc[4] = {L2E, L2E, 2.0f * L2E, L2E};
  const i32x4 zeroi = {0, 0, 0, 0};
  float scB[4];
#pragma unroll
  for (int p = 0; p < 4; ++p) scB[p] = gsc[p] * (1.f / 8388608.f);  // 2^-23

// plane(layer, parity P, level L) within this group's region
#define PL(layer, P, L) (hq + ((((layer) * 2 + (P)) * 2) + (L)) * 1280)

  if (wr < 4) {
    // =================== E: layer 1, step k ===================
    const int row = 16 * wr + s;
    i32x4 aW0[4], aW1[4];
#pragma unroll
    for (int p = 0; p < 4; ++p)
      quantW16(Whh1 + (size_t)(p * 64 + row) * 64 + 16 * g, aW0[p], aW1[p]);
    float bias1c[4][4], wih1c[4][4];
#pragma unroll
    for (int p = 0; p < 4; ++p)
#pragma unroll
      for (int r = 0; r < 4; ++r) {
        const int rr = p * 64 + 16 * wr + 4 * g + r;
        bias1c[p][r] = (bih1[rr] + bhh1[rr]) * gsc[p];
        wih1c[p][r] = Wih1[rr] * gsc[p];
      }
    float c1[4] = {0.f, 0.f, 0.f, 0.f};
    const int hwA = s * 80 + 16 * wr + 4 * g;    // h-write byte offset
    const float* xrow = (const float*)(smem + q * XPG + s * XPITCH);

#define EB(KK, P)                                                             \
  {                                                                           \
    const float x = xrow[KK];                                                 \
    const i32x4 B0 = *(const i32x4*)(smem + PL(0, (P) ^ 1, 0) + boff);        \
    const i32x4 B1 = *(const i32x4*)(smem + PL(0, (P) ^ 1, 1) + boff);        \
    i32x4 S00[4], SB[4];                                                      \
    __builtin_amdgcn_s_setprio(1);                                            \
    _Pragma("unroll") for (int p = 0; p < 4; ++p)                             \
        S00[p] = mfma_i8(aW0[p], B0, zeroi);                                  \
    _Pragma("unroll") for (int p = 0; p < 4; ++p)                             \
        SB[p] = mfma_i8(aW1[p], B0, zeroi);                                   \
    _Pragma("unroll") for (int p = 0; p < 4; ++p)                             \
        SB[p] = mfma_i8(aW0[p], B1, SB[p]);                                   \
    __builtin_amdgcn_s_setprio(0);                                            \
    float ga[4][4];                                                           \
    _Pragma("unroll") for (int p = 0; p < 4; ++p) {                           \
      _Pragma("unroll") for (int r = 0; r < 4; ++r) {                         \
        const int gi = (S00[p][r] << 8) + SB[p][r];                           \
        const float base = fmaf(wih1c[p][r], x, bias1c[p][r]);                \
        ga[p][r] = fmaf((float)gi, scB[p], base);                             \
      }                                                                       \
    }                                                                         \
    float h1n[4];                                                             \
    _Pragma("unroll") for (int r = 0; r < 4; ++r)                             \
        cell2(ga[0][r], ga[1][r], ga[2][r], ga[3][r], c1[r], h1n[r]);         \
    unsigned L0, L1;                                                          \
    quantH4(h1n, L0, L1);                                                     \
    *(unsigned*)(smem + PL(0, (P), 0) + hwA) = L0;                            \
    *(unsigned*)(smem + PL(0, (P), 1) + hwA) = L1;                            \
  }

    EB(0, 0);
    __syncthreads();
#pragma unroll 1
    for (int kb = 1; kb <= 509; kb += 2) {
      EB(kb, 1);
      __syncthreads();
      EB(kb + 1, 0);
      __syncthreads();
    }
    EB(511, 1);
    __syncthreads();
    __syncthreads();  // iter 512 (E idle; O computes h2(511))
  } else {
    // =================== O: layer 2, step k-1 ===================
    const int ow = wr - 4;
    const int row = 16 * ow + s;
    i32x4 bW0[4], bW1[4], cW0[4], cW1[4];
#pragma unroll
    for (int p = 0; p < 4; ++p) {
      quantW16(Wih2 + (size_t)(p * 64 + row) * 64 + 16 * g, bW0[p], bW1[p]);
      quantW16(Whh2 + (size_t)(p * 64 + row) * 64 + 16 * g, cW0[p], cW1[p]);
    }
    float bias2c[4][4], wlinc[4];
#pragma unroll
    for (int p = 0; p < 4; ++p)
#pragma unroll
      for (int r = 0; r < 4; ++r) {
        const int rr = p * 64 + 16 * ow + 4 * g + r;
        bias2c[p][r] = (bih2[rr] + bhh2[rr]) * gsc[p];
      }
#pragma unroll
    for (int r = 0; r < 4; ++r) wlinc[r] = Wlin[16 * ow + 4 * g + r];
    float c2[4] = {0.f, 0.f, 0.f, 0.f};
    const int hwA = s * 80 + 16 * ow + 4 * g;
    char* ringb = smem + ringB + ow * 64 + s * 4;

#define OFLUSH(KK)                                                            \
  if ((KK) >= 66 && (((KK)-2) & 63) == 0) {                                   \
    const int base = (KK)-66;                                                 \
    const int thr = ow * 64 + lane;                                           \
    const int ss2 = thr & 15, grp = thr >> 4;                                 \
    _Pragma("unroll") for (int qq = 0; qq < 4; ++qq) {                        \
      const int idx = base + grp * 4 + qq;                                    \
      const char* op = smem + ringB + (idx & 127) * 256 + ss2 * 4;            \
      const float v = *(const float*)(op) + *(const float*)(op + 64) +        \
                      *(const float*)(op + 128) + *(const float*)(op + 192) + \
                      bl0;                                                    \
      out[(size_t)(s0g + ss2) * 511 + idx] = v;                               \
    }                                                                         \
  }

#define OB(KK, P)                                                             \
  {                                                                           \
    const i32x4 B10 = *(const i32x4*)(smem + PL(0, (P) ^ 1, 0) + boff);       \
    const i32x4 B11 = *(const i32x4*)(smem + PL(0, (P) ^ 1, 1) + boff);       \
    const i32x4 B20 = *(const i32x4*)(smem + PL(1, (P), 0) + boff);           \
    const i32x4 B21 = *(const i32x4*)(smem + PL(1, (P), 1) + boff);           \
    i32x4 S00[4], SB[4];                                                      \
    __builtin_amdgcn_s_setprio(1);                                            \
    _Pragma("unroll") for (int p = 0; p < 4; ++p)                             \
        S00[p] = mfma_i8(bW0[p], B10, zeroi);                                 \
    _Pragma("unroll") for (int p = 0; p < 4; ++p)                             \
        SB[p] = mfma_i8(bW1[p], B10, zeroi);                                  \
    _Pragma("unroll") for (int p = 0; p < 4; ++p)                             \
        S00[p] = mfma_i8(cW0[p], B20, S00[p]);                                \
    _Pragma("unroll") for (int p = 0; p < 4; ++p)                             \
        SB[p] = mfma_i8(bW0[p], B11, SB[p]);                                  \
    _Pragma("unroll") for (int p = 0; p < 4; ++p)                             \
        SB[p] = mfma_i8(cW1[p], B20, SB[p]);                                  \
    _Pragma("unroll") for (int p = 0; p < 4; ++p)                             \
        SB[p] = mfma_i8(cW0[p], B21, SB[p]);                                  \
    __builtin_amdgcn_s_setprio(0);                                            \
    float ga[4][4];                                                           \
    _Pragma("unroll") for (int p = 0; p < 4; ++p) {                           \
      _Pragma("unroll") for (int r = 0; r < 4; ++r) {                         \
        const int gi = (S00[p][r] << 8) + SB[p][r];                           \
        ga[p][r] = fmaf((float)gi, scB[p], bias2c[p][r]);                     \
      }                                                                       \
    }                                                                         \
    float h2n[4];                                                             \
    _Pragma("unroll") for (int r = 0; r < 4; ++r)                             \
        cell2(ga[0][r], ga[1][r], ga[2][r], ga[3][r], c2[r], h2n[r]);         \
    unsigned L0, L1;                                                          \
    quantH4(h2n, L0, L1);                                                     \
    *(unsigned*)(smem + PL(1, (P) ^ 1, 0) + hwA) = L0;                        \
    *(unsigned*)(smem + PL(1, (P) ^ 1, 1) + hwA) = L1;                        \
    if ((KK) >= 2) {                                                          \
      float pw = wlinc[0] * h2n[0];                                           \
      pw = fmaf(wlinc[1], h2n[1], pw);                                        \
      pw = fmaf(wlinc[2], h2n[2], pw);                                        \
      pw = fmaf(wlinc[3], h2n[3], pw);                                        \
      pw += __shfl_xor(pw, 16, 64);                                           \
      pw += __shfl_xor(pw, 32, 64);                                           \
      if (g == 0) *(float*)(ringb + (((KK)-2) & 127) * 256) = pw;             \
    }                                                                         \
  }

    __syncthreads();  // k = 0 (O idle)
#pragma unroll 1
    for (int kb = 1; kb <= 509; kb += 2) {
      OB(kb, 1);
      __syncthreads();
      OFLUSH(kb + 1);
      OB(kb + 1, 0);
      __syncthreads();
    }
    OB(511, 1);
    __syncthreads();
    OB(512, 0);
    __syncthreads();
    // tail flush: out positions 448..510
    {
      const int thr = ow * 64 + lane;
      for (int e = thr; e < 63 * 16; e += 256) {
        const int ss2 = e & 15, off = e >> 4;
        const int idx = 448 + off;
        const char* op = smem + ringB + (idx & 127) * 256 + ss2 * 4;
        const float v = *(const float*)(op) + *(const float*)(op + 64) +
                        *(const float*)(op + 128) + *(const float*)(op + 192) + bl0;
        out[(size_t)(s0g + ss2) * 511 + idx] = v;
      }
    }
  }
}

extern "C" void kernel_launch(void* const* d_in, const int* in_sizes, int n_in,
                              void* d_out, int out_size, void* d_ws, size_t ws_size,
                              hipStream_t stream) {
  const float* y    = (const float*)d_in[0];
  const float* Wih1 = (const float*)d_in[1];
  const float* Whh1 = (const float*)d_in[2];
  const float* bih1 = (const float*)d_in[3];
  const float* bhh1 = (const float*)d_in[4];
  const float* Wih2 = (const float*)d_in[5];
  const float* Whh2 = (const float*)d_in[6];
  const float* bih2 = (const float*)d_in[7];
  const float* bhh2 = (const float*)d_in[8];
  const float* Wlin = (const float*)d_in[9];
  const float* blin = (const float*)d_in[10];
  float* out = (float*)d_out;

  hipFuncSetAttribute((const void*)lstm2_r16,
                      hipFuncAttributeMaxDynamicSharedMemorySize, LDS_BYTES);
  lstm2_r16<<<dim3(64), dim3(1024), LDS_BYTES, stream>>>(
      y, Wih1, Whh1, bih1, bhh1, Wih2, Whh2, bih2, bhh2, Wlin, blin, out);
}

// Round 17
// 1612.040 us; speedup vs baseline: 1.0034x; 1.0034x over previous
//
#include <hip/hip_runtime.h>

// 2-layer LSTM (H=64, D=1), N=2048, T=512 — R17 = R16 with FIXED LAUNCH
// BOUNDS: __launch_bounds__(1024, 1). R16's (1024,4) capped VGPRs at 64 ->
// O-waves' 64 VGPRs of i8 weights spilled to scratch, reloaded every step
// (3x slowdown, WRITE_SIZE 4KB->10MB). (1024,1) gives a >=128-VGPR budget;
// the 152KB LDS already pins 1 block/CU = 4 waves/SIMD.
// Structure: 64 blocks x 1024 thr; waves 0-7 = E/O pipeline for samples
// [b*32,+16), waves 8-15 = same for [+16,+32). i8 2-level fixed-point MFMA,
// exact int combine (S00<<8)+SB, exp2-prescale, v_exp -src fold.

typedef __attribute__((ext_vector_type(4))) int i32x4;
typedef __attribute__((ext_vector_type(4))) float f32x4;

#define XPITCH 2060              // 515 words (odd) -> conflict-free x reads
#define XPG 32960                // per-group x region (16 * 2060)
#define HB0 65920                // h planes: group q at HB0 + q*10240
#define HBG 10240
#define RING0 86400              // out ring: group q at RING0 + q*32768
#define LDS_BYTES 151936
#define L2E 1.44269504f
#define N2L2E (-2.8853900817779268f)

__device__ __forceinline__ float fast_rcp(float x) { return __builtin_amdgcn_rcpf(x); }
__device__ __forceinline__ float exp2_f(float x) {
  float r; asm("v_exp_f32 %0, %1" : "=v"(r) : "v"(x)); return r;
}
__device__ __forceinline__ float exp2_nf(float x) {  // 2^(-x), negate folded
  float r; asm("v_exp_f32 %0, -%1" : "=v"(r) : "v"(x)); return r;
}
__device__ __forceinline__ i32x4 mfma_i8(i32x4 a, i32x4 b, i32x4 c) {
  return __builtin_amdgcn_mfma_i32_16x16x64_i8(a, b, c, 0, 0, 0);
}
// gates pre-scaled: i,f,o by log2e; g by 2log2e. 5 exp2 + 3 rcp.
__device__ __forceinline__ void cell2(float i, float f, float g, float o,
                                      float& c, float& h) {
  const float ei = exp2_nf(i), ef = exp2_nf(f), eg = exp2_nf(g), eo = exp2_nf(o);
  const float P = (1.f - eg) * fast_rcp((1.f + ei) * (1.f + eg));
  c = fmaf(c, fast_rcp(1.f + ef), P);
  const float cc = fminf(15.f, fmaxf(-15.f, c));
  const float ec = exp2_f(N2L2E * cc);
  h = (1.f - ec) * fast_rcp((1.f + eo) * (1.f + ec));
}
// Quantize 16 consecutive f32 weights (|W|<=1/8) to two i8 levels, packed.
__device__ __forceinline__ void quantW16(const float* p, i32x4& w0v, i32x4& w1v) {
  int b0[16], b1[16];
#pragma unroll
  for (int e = 0; e < 16; ++e) {
    const float v = p[e];
    const float q0 = rintf(v * 512.f);
    const float r = v - q0 * (1.f / 512.f);
    const float q1 = fminf(127.f, fmaxf(-127.f, rintf(r * 131072.f)));
    b0[e] = (int)q0;
    b1[e] = (int)q1;
  }
#pragma unroll
  for (int d = 0; d < 4; ++d) {
    w0v[d] = (b0[4 * d] & 255) | ((b0[4 * d + 1] & 255) << 8) |
             ((b0[4 * d + 2] & 255) << 16) | ((b0[4 * d + 3] & 255) << 24);
    w1v[d] = (b1[4 * d] & 255) | ((b1[4 * d + 1] & 255) << 8) |
             ((b1[4 * d + 2] & 255) << 16) | ((b1[4 * d + 3] & 255) << 24);
  }
}
// Quantize 4 h values (|h|<=1) to two packed i8-level dwords.
__device__ __forceinline__ void quantH4(const float* h, unsigned& L0, unsigned& L1) {
  int q0[4], q1[4];
#pragma unroll
  for (int r = 0; r < 4; ++r) {
    const float q0f = rintf(h[r] * 64.f);
    q0[r] = (int)q0f;
    const float rr = h[r] - q0f * 0.015625f;
    const float q1f = fminf(127.f, fmaxf(-127.f, rintf(rr * 16384.f)));
    q1[r] = (int)q1f;
  }
  L0 = (q0[0] & 255) | ((q0[1] & 255) << 8) | ((q0[2] & 255) << 16) |
       ((q0[3] & 255) << 24);
  L1 = (q1[0] & 255) | ((q1[1] & 255) << 8) | ((q1[2] & 255) << 16) |
       ((q1[3] & 255) << 24);
}

__global__ __launch_bounds__(1024, 1) void lstm2_r17(
    const float* __restrict__ y, const float* __restrict__ Wih1,
    const float* __restrict__ Whh1, const float* __restrict__ bih1,
    const float* __restrict__ bhh1, const float* __restrict__ Wih2,
    const float* __restrict__ Whh2, const float* __restrict__ bih2,
    const float* __restrict__ bhh2, const float* __restrict__ Wlin,
    const float* __restrict__ blin, float* __restrict__ out) {
  extern __shared__ char smem[];
  const int tid = threadIdx.x;
  const int w = tid >> 6;          // wave 0..15
  const int q = w >> 3;            // sample group 0/1
  const int wr = w & 7;            // role wave within group (0-3 E, 4-7 O)
  const int lane = tid & 63;
  const int g = lane >> 4;
  const int s = lane & 15;
  const int s0g = blockIdx.x * 32 + q * 16;

  // ---- stage x for 32 samples ----
  for (int i = tid; i < 32 * 512; i += 1024) {
    const int ss = i >> 9, t = i & 511;
    *(float*)(smem + (ss >> 4) * XPG + (ss & 15) * XPITCH + t * 4) =
        y[(size_t)(blockIdx.x * 32 + ss) * 512 + t];
  }
  // ---- zero all h planes (both groups) ----
  for (int i = tid; i < 20480 / 4; i += 1024) *(float*)(smem + HB0 + i * 4) = 0.f;
  const float bl0 = blin[0];
  __syncthreads();

  const int hq = HB0 + q * HBG;                  // group plane base
  const int ringB = RING0 + q * 32768;           // group ring base
  const int boff = s * 80 + 16 * g;              // B-fragment byte offset
  const float gsc[4] = {L2E, L2E, 2.0f * L2E, L2E};
  const i32x4 zeroi = {0, 0, 0, 0};
  float scB[4];
#pragma unroll
  for (int p = 0; p < 4; ++p) scB[p] = gsc[p] * (1.f / 8388608.f);  // 2^-23

// plane(layer, parity P, level L) within this group's region
#define PL(layer, P, L) (hq + ((((layer) * 2 + (P)) * 2) + (L)) * 1280)

  if (wr < 4) {
    // =================== E: layer 1, step k ===================
    const int row = 16 * wr + s;
    i32x4 aW0[4], aW1[4];
#pragma unroll
    for (int p = 0; p < 4; ++p)
      quantW16(Whh1 + (size_t)(p * 64 + row) * 64 + 16 * g, aW0[p], aW1[p]);
    float bias1c[4][4], wih1c[4][4];
#pragma unroll
    for (int p = 0; p < 4; ++p)
#pragma unroll
      for (int r = 0; r < 4; ++r) {
        const int rr = p * 64 + 16 * wr + 4 * g + r;
        bias1c[p][r] = (bih1[rr] + bhh1[rr]) * gsc[p];
        wih1c[p][r] = Wih1[rr] * gsc[p];
      }
    float c1[4] = {0.f, 0.f, 0.f, 0.f};
    const int hwA = s * 80 + 16 * wr + 4 * g;    // h-write byte offset
    const float* xrow = (const float*)(smem + q * XPG + s * XPITCH);

#define EB(KK, P)                                                             \
  {                                                                           \
    const float x = xrow[KK];                                                 \
    const i32x4 B0 = *(const i32x4*)(smem + PL(0, (P) ^ 1, 0) + boff);        \
    const i32x4 B1 = *(const i32x4*)(smem + PL(0, (P) ^ 1, 1) + boff);        \
    i32x4 S00[4], SB[4];                                                      \
    __builtin_amdgcn_s_setprio(1);                                            \
    _Pragma("unroll") for (int p = 0; p < 4; ++p)                             \
        S00[p] = mfma_i8(aW0[p], B0, zeroi);                                  \
    _Pragma("unroll") for (int p = 0; p < 4; ++p)                             \
        SB[p] = mfma_i8(aW1[p], B0, zeroi);                                   \
    _Pragma("unroll") for (int p = 0; p < 4; ++p)                             \
        SB[p] = mfma_i8(aW0[p], B1, SB[p]);                                   \
    __builtin_amdgcn_s_setprio(0);                                            \
    float ga[4][4];                                                           \
    _Pragma("unroll") for (int p = 0; p < 4; ++p) {                           \
      _Pragma("unroll") for (int r = 0; r < 4; ++r) {                         \
        const int gi = (S00[p][r] << 8) + SB[p][r];                           \
        const float base = fmaf(wih1c[p][r], x, bias1c[p][r]);                \
        ga[p][r] = fmaf((float)gi, scB[p], base);                             \
      }                                                                       \
    }                                                                         \
    float h1n[4];                                                             \
    _Pragma("unroll") for (int r = 0; r < 4; ++r)                             \
        cell2(ga[0][r], ga[1][r], ga[2][r], ga[3][r], c1[r], h1n[r]);         \
    unsigned L0, L1;                                                          \
    quantH4(h1n, L0, L1);                                                     \
    *(unsigned*)(smem + PL(0, (P), 0) + hwA) = L0;                            \
    *(unsigned*)(smem + PL(0, (P), 1) + hwA) = L1;                            \
  }

    EB(0, 0);
    __syncthreads();
#pragma unroll 1
    for (int kb = 1; kb <= 509; kb += 2) {
      EB(kb, 1);
      __syncthreads();
      EB(kb + 1, 0);
      __syncthreads();
    }
    EB(511, 1);
    __syncthreads();
    __syncthreads();  // iter 512 (E idle; O computes h2(511))
  } else {
    // =================== O: layer 2, step k-1 ===================
    const int ow = wr - 4;
    const int row = 16 * ow + s;
    i32x4 bW0[4], bW1[4], cW0[4], cW1[4];
#pragma unroll
    for (int p = 0; p < 4; ++p) {
      quantW16(Wih2 + (size_t)(p * 64 + row) * 64 + 16 * g, bW0[p], bW1[p]);
      quantW16(Whh2 + (size_t)(p * 64 + row) * 64 + 16 * g, cW0[p], cW1[p]);
    }
    float bias2c[4][4], wlinc[4];
#pragma unroll
    for (int p = 0; p < 4; ++p)
#pragma unroll
      for (int r = 0; r < 4; ++r) {
        const int rr = p * 64 + 16 * ow + 4 * g + r;
        bias2c[p][r] = (bih2[rr] + bhh2[rr]) * gsc[p];
      }
#pragma unroll
    for (int r = 0; r < 4; ++r) wlinc[r] = Wlin[16 * ow + 4 * g + r];
    float c2[4] = {0.f, 0.f, 0.f, 0.f};
    const int hwA = s * 80 + 16 * ow + 4 * g;
    char* ringb = smem + ringB + ow * 64 + s * 4;

#define OFLUSH(KK)                                                            \
  if ((KK) >= 66 && (((KK)-2) & 63) == 0) {                                   \
    const int base = (KK)-66;                                                 \
    const int thr = ow * 64 + lane;                                           \
    const int ss2 = thr & 15, grp = thr >> 4;                                 \
    _Pragma("unroll") for (int qq = 0; qq < 4; ++qq) {                        \
      const int idx = base + grp * 4 + qq;                                    \
      const char* op = smem + ringB + (idx & 127) * 256 + ss2 * 4;            \
      const float v = *(const float*)(op) + *(const float*)(op + 64) +        \
                      *(const float*)(op + 128) + *(const float*)(op + 192) + \
                      bl0;                                                    \
      out[(size_t)(s0g + ss2) * 511 + idx] = v;                               \
    }                                                                         \
  }

#define OB(KK, P)                                                             \
  {                                                                           \
    const i32x4 B10 = *(const i32x4*)(smem + PL(0, (P) ^ 1, 0) + boff);       \
    const i32x4 B11 = *(const i32x4*)(smem + PL(0, (P) ^ 1, 1) + boff);       \
    const i32x4 B20 = *(const i32x4*)(smem + PL(1, (P), 0) + boff);           \
    const i32x4 B21 = *(const i32x4*)(smem + PL(1, (P), 1) + boff);           \
    i32x4 S00[4], SB[4];                                                      \
    __builtin_amdgcn_s_setprio(1);                                            \
    _Pragma("unroll") for (int p = 0; p < 4; ++p)                             \
        S00[p] = mfma_i8(bW0[p], B10, zeroi);                                 \
    _Pragma("unroll") for (int p = 0; p < 4; ++p)                             \
        SB[p] = mfma_i8(bW1[p], B10, zeroi);                                  \
    _Pragma("unroll") for (int p = 0; p < 4; ++p)                             \
        S00[p] = mfma_i8(cW0[p], B20, S00[p]);                                \
    _Pragma("unroll") for (int p = 0; p < 4; ++p)                             \
        SB[p] = mfma_i8(bW0[p], B11, SB[p]);                                  \
    _Pragma("unroll") for (int p = 0; p < 4; ++p)                             \
        SB[p] = mfma_i8(cW1[p], B20, SB[p]);                                  \
    _Pragma("unroll") for (int p = 0; p < 4; ++p)                             \
        SB[p] = mfma_i8(cW0[p], B21, SB[p]);                                  \
    __builtin_amdgcn_s_setprio(0);                                            \
    float ga[4][4];                                                           \
    _Pragma("unroll") for (int p = 0; p < 4; ++p) {                           \
      _Pragma("unroll") for (int r = 0; r < 4; ++r) {                         \
        const int gi = (S00[p][r] << 8) + SB[p][r];                           \
        ga[p][r] = fmaf((float)gi, scB[p], bias2c[p][r]);                     \
      }                                                                       \
    }                                                                         \
    float h2n[4];                                                             \
    _Pragma("unroll") for (int r = 0; r < 4; ++r)                             \
        cell2(ga[0][r], ga[1][r], ga[2][r], ga[3][r], c2[r], h2n[r]);         \
    unsigned L0, L1;                                                          \
    quantH4(h2n, L0, L1);                                                     \
    *(unsigned*)(smem + PL(1, (P) ^ 1, 0) + hwA) = L0;                        \
    *(unsigned*)(smem + PL(1, (P) ^ 1, 1) + hwA) = L1;                        \
    if ((KK) >= 2) {                                                          \
      float pw = wlinc[0] * h2n[0];                                           \
      pw = fmaf(wlinc[1], h2n[1], pw);                                        \
      pw = fmaf(wlinc[2], h2n[2], pw);                                        \
      pw = fmaf(wlinc[3], h2n[3], pw);                                        \
      pw += __shfl_xor(pw, 16, 64);                                           \
      pw += __shfl_xor(pw, 32, 64);                                           \
      if (g == 0) *(float*)(ringb + (((KK)-2) & 127) * 256) = pw;             \
    }                                                                         \
  }

    __syncthreads();  // k = 0 (O idle)
#pragma unroll 1
    for (int kb = 1; kb <= 509; kb += 2) {
      OB(kb, 1);
      __syncthreads();
      OFLUSH(kb + 1);
      OB(kb + 1, 0);
      __syncthreads();
    }
    OB(511, 1);
    __syncthreads();
    OB(512, 0);
    __syncthreads();
    // tail flush: out positions 448..510
    {
      const int thr = ow * 64 + lane;
      for (int e = thr; e < 63 * 16; e += 256) {
        const int ss2 = e & 15, off = e >> 4;
        const int idx = 448 + off;
        const char* op = smem + ringB + (idx & 127) * 256 + ss2 * 4;
        const float v = *(const float*)(op) + *(const float*)(op + 64) +
                        *(const float*)(op + 128) + *(const float*)(op + 192) + bl0;
        out[(size_t)(s0g + ss2) * 511 + idx] = v;
      }
    }
  }
}

extern "C" void kernel_launch(void* const* d_in, const int* in_sizes, int n_in,
                              void* d_out, int out_size, void* d_ws, size_t ws_size,
                              hipStream_t stream) {
  const float* y    = (const float*)d_in[0];
  const float* Wih1 = (const float*)d_in[1];
  const float* Whh1 = (const float*)d_in[2];
  const float* bih1 = (const float*)d_in[3];
  const float* bhh1 = (const float*)d_in[4];
  const float* Wih2 = (const float*)d_in[5];
  const float* Whh2 = (const float*)d_in[6];
  const float* bih2 = (const float*)d_in[7];
  const float* bhh2 = (const float*)d_in[8];
  const float* Wlin = (const float*)d_in[9];
  const float* blin = (const float*)d_in[10];
  float* out = (float*)d_out;

  hipFuncSetAttribute((const void*)lstm2_r17,
                      hipFuncAttributeMaxDynamicSharedMemorySize, LDS_BYTES);
  lstm2_r17<<<dim3(64), dim3(1024), LDS_BYTES, stream>>>(
      y, Wih1, Whh1, bih1, bhh1, Wih2, Whh2, bih2, bhh2, Wlin, blin, out);
}